// Round 6
// baseline (308.958 us; speedup 1.0000x reference)
//
#include <hip/hip_runtime.h>

// (1/sqrt(3)) * log2(e): folds softmax scale AND exp->exp2 into q.
// Softmax is shift-invariant; scores are O(+-4) -> no max-subtraction needed
// in fp32 (validated rounds 1-5: identical math passed absmax check).
#define QSCALE 0.83294038f

__device__ __forceinline__ int seg_of(int s) {
    // SEG = [0, 1*5, 2*3, 3, 4*6]
    return (s == 0) ? 0 : (s < 6) ? 1 : (s < 9) ? 2 : (s == 9) ? 3 : 4;
}

// 4 threads per batch element: lane quad = {(h0,kh0),(h1,kh0),(h0,kh1),(h1,kh1)}
//   h  = T&1        : head (3 dims of Q/K/V/ctx)
//   kh = (T>>1)&1   : key half (keys kh*8 .. kh*8+7)
// K/V register footprint = 8*3*2 = 48 floats -> total live ~110 < 128 VGPR:
// spill-proof at the allocator's default 4 waves/SIMD (r4/r5 showed 128 is a
// hard wall; this structure fits UNDER it instead of fighting it).
// All exchange via 7 __shfl_xor per query (lane^2: merge key-half partial
// exp-sums -- exact, sums are order-free; lane^1: swap ctx across heads).
__global__ __launch_bounds__(256) void attn_seg_kernel(
    const float* __restrict__ x,
    const float* __restrict__ Wq, const float* __restrict__ bq,
    const float* __restrict__ Wk, const float* __restrict__ bk,
    const float* __restrict__ Wv, const float* __restrict__ bv,
    const float* __restrict__ Wo, const float* __restrict__ bo,
    float* __restrict__ out, int nelems)
{
    const int T = blockIdx.x * 256 + threadIdx.x;
    const int e = T >> 2;
    if (e >= nelems) return;          // whole lane-quads drop together
    const int h  = T & 1;
    const int kh = (T >> 1) & 1;
    const int kbase = kh << 3;        // first owned key
    const int hw = h * 18;            // float offset of head's 3 weight rows
    const int hb = h * 3;

    const float* __restrict__ xe = x + (size_t)e * 96;
    float* __restrict__ oe = out + (size_t)e * 96;

    // ---- pass 1: K,V for own 8 keys, own head. Weight slice (18+18 floats)
    // reloads only at per-lane segment boundaries: si in {0,1,2,6} covers
    // kh=0 (segs 0,1,1,1,1,1,2,2) and kh=1 (segs 2,3,4,4,4,4,4,4). L1-hot.
    float K[8][3], V[8][3];
    float wk[18], wv[18], bk3[3], bv3[3];
    #pragma unroll
    for (int si = 0; si < 8; ++si) {
        if (si == 0 || si == 1 || si == 2 || si == 6) {   // compile-time
            const int sg = seg_of(kbase + si);            // per-lane (VALU)
            const float* wkp = Wk + sg * 36 + hw;         // 8B-aligned
            const float* wvp = Wv + sg * 36 + hw;
            #pragma unroll
            for (int i = 0; i < 9; ++i) {
                float2 a = *(const float2*)(wkp + 2 * i);
                wk[2*i] = a.x; wk[2*i+1] = a.y;
                float2 b = *(const float2*)(wvp + 2 * i);
                wv[2*i] = b.x; wv[2*i+1] = b.y;
            }
            const float* bkp = bk + sg * 6 + hb;
            const float* bvp = bv + sg * 6 + hb;
            bk3[0]=bkp[0]; bk3[1]=bkp[1]; bk3[2]=bkp[2];
            bv3[0]=bvp[0]; bv3[1]=bvp[1]; bv3[2]=bvp[2];
        }
        const float* xr = xe + (kbase + si) * 6;          // 8B-aligned
        float2 a = *(const float2*)(xr);
        float2 b = *(const float2*)(xr + 2);
        float2 c = *(const float2*)(xr + 4);
        #pragma unroll
        for (int j = 0; j < 3; ++j) {
            K[si][j] = bk3[j] + a.x*wk[j*6+0] + a.y*wk[j*6+1] + b.x*wk[j*6+2]
                              + b.y*wk[j*6+3] + c.x*wk[j*6+4] + c.y*wk[j*6+5];
            V[si][j] = bv3[j] + a.x*wv[j*6+0] + a.y*wv[j*6+1] + b.x*wv[j*6+2]
                              + b.y*wv[j*6+3] + c.x*wv[j*6+4] + c.y*wv[j*6+5];
        }
    }

    // ---- hoist own 3 Wo rows, reordered own-ctx-first (static indexing;
    // avoids runtime-h indexing into a 6-wide ctx array -> no scratch).
    float wo_own[9], wo_oth[9], bo3[3];
    {
        const int ob = 3 - hb;        // other head's ctx column base
        #pragma unroll
        for (int i = 0; i < 3; ++i) {
            const float* wr = Wo + (hb + i) * 6;
            wo_own[i*3+0] = wr[hb+0]; wo_own[i*3+1] = wr[hb+1]; wo_own[i*3+2] = wr[hb+2];
            wo_oth[i*3+0] = wr[ob+0]; wo_oth[i*3+1] = wr[ob+1]; wo_oth[i*3+2] = wr[ob+2];
            bo3[i] = bo[hb + i];
        }
    }

    // Launder x base: pass-2 row reloads must not be CSE'd with pass-1 loads
    // (would extend 24+ live ranges across the kernel -> spill; r5 lesson).
    const float* xq = xe;
    asm volatile("" : "+v"(xq));

    // ---- pass 2: 16 queries. q is wave-uniform; all K/V indexing static.
    #pragma unroll 2
    for (int q = 0; q < 16; ++q) {
        const int sg = seg_of(q);                   // uniform
        const float* wqp = Wq + sg * 36 + hw;
        float wq[18];
        #pragma unroll
        for (int i = 0; i < 9; ++i) {
            float2 a = *(const float2*)(wqp + 2 * i);
            wq[2*i] = a.x; wq[2*i+1] = a.y;
        }
        const float* bqp = bq + sg * 6 + hb;
        const float qb0 = bqp[0], qb1 = bqp[1], qb2 = bqp[2];

        const float* xr = xq + q * 6;               // L1-hot reload
        float2 a = *(const float2*)(xr);
        float2 b = *(const float2*)(xr + 2);
        float2 c = *(const float2*)(xr + 4);

        const float q0 = (qb0 + a.x*wq[0]  + a.y*wq[1]  + b.x*wq[2]
                              + b.y*wq[3]  + c.x*wq[4]  + c.y*wq[5])  * QSCALE;
        const float q1 = (qb1 + a.x*wq[6]  + a.y*wq[7]  + b.x*wq[8]
                              + b.y*wq[9]  + c.x*wq[10] + c.y*wq[11]) * QSCALE;
        const float q2 = (qb2 + a.x*wq[12] + a.y*wq[13] + b.x*wq[14]
                              + b.y*wq[15] + c.x*wq[16] + c.y*wq[17]) * QSCALE;

        // own 8 keys: score -> exp2 -> partial sum/PV (8 independent chains)
        float ss = 0.f, c0 = 0.f, c1 = 0.f, c2 = 0.f;
        #pragma unroll
        for (int k = 0; k < 8; ++k) {
            float ee = __builtin_amdgcn_exp2f(q0*K[k][0] + q1*K[k][1] + q2*K[k][2]);
            ss += ee;
            c0 += ee*V[k][0]; c1 += ee*V[k][1]; c2 += ee*V[k][2];
        }

        // merge key halves (lane^2) -- exact: exp-sums are order-free
        ss += __shfl_xor(ss, 2);
        c0 += __shfl_xor(c0, 2);
        c1 += __shfl_xor(c1, 2);
        c2 += __shfl_xor(c2, 2);
        const float inv = __builtin_amdgcn_rcpf(ss);
        c0 *= inv; c1 *= inv; c2 *= inv;

        // swap ctx across heads (lane^1): both sides now hold full ctx[6]
        const float d0 = __shfl_xor(c0, 1);
        const float d1 = __shfl_xor(c1, 1);
        const float d2 = __shfl_xor(c2, 1);

        const float o0 = bo3[0] + c0*wo_own[0] + c1*wo_own[1] + c2*wo_own[2]
                                + d0*wo_oth[0] + d1*wo_oth[1] + d2*wo_oth[2];
        const float o1 = bo3[1] + c0*wo_own[3] + c1*wo_own[4] + c2*wo_own[5]
                                + d0*wo_oth[3] + d1*wo_oth[4] + d2*wo_oth[5];
        const float o2 = bo3[2] + c0*wo_own[6] + c1*wo_own[7] + c2*wo_own[8]
                                + d0*wo_oth[6] + d1*wo_oth[7] + d2*wo_oth[8];

        // split stores: kh=0 lanes store queries 0-7, kh=1 stores 8-15
        if (((q >> 3) & 1) == kh) {
            float* op = oe + q * 6 + hb;
            op[0] = o0; op[1] = o1; op[2] = o2;
        }
    }
}

extern "C" void kernel_launch(void* const* d_in, const int* in_sizes, int n_in,
                              void* d_out, int out_size, void* d_ws, size_t ws_size,
                              hipStream_t stream) {
    const float* x  = (const float*)d_in[0];
    const float* Wq = (const float*)d_in[1];
    const float* bq = (const float*)d_in[2];
    const float* Wk = (const float*)d_in[3];
    const float* bk = (const float*)d_in[4];
    const float* Wv = (const float*)d_in[5];
    const float* bv = (const float*)d_in[6];
    const float* Wo = (const float*)d_in[7];
    const float* bo = (const float*)d_in[8];
    float* out = (float*)d_out;

    const int nelems  = in_sizes[0] / 96;          // batch elements
    const int nthread = nelems * 4;                // 4 threads per element
    const int grid    = (nthread + 255) / 256;
    attn_seg_kernel<<<grid, 256, 0, stream>>>(x, Wq, bq, Wk, bk, Wv, bv, Wo, bo, out, nelems);
}

// Round 7
// 215.865 us; speedup vs baseline: 1.4313x; 1.4313x over previous
//
#include <hip/hip_runtime.h>

// (1/sqrt(3)) * log2(e): folds softmax scale AND exp->exp2 into q.
// Softmax is shift-invariant; scores are O(+-4) -> no max-subtraction needed
// in fp32 (validated rounds 1-6: identical math passed absmax check).
#define QSCALE 0.83294038f

// LDS layout (dwords):
//   KV:  [elem e: 0..63][pos k: 0..15][12: K0..5,V0..5]  stride_e = 194
//        (16*12 + 2 pad: 8B-aligned rows; lane bank offset 2 -> 4-way b64, budgeted)
//   OUT: [elem e][pos s][6]                               stride_e = 97
//        (odd stride -> 2-way bank spread = conflict-free for b32)
#define KV_STRIDE 194
#define OUT_STRIDE 97
#define KV_FLOATS (64 * KV_STRIDE)          // 12416
#define OUT_OFF   KV_FLOATS
#define LDS_FLOATS (KV_FLOATS + 64 * OUT_STRIDE)   // 18624 floats = 74496 B -> 2 blocks/CU

__device__ __forceinline__ int seg_of(int s) {
    // SEG = [0, 1*5, 2*3, 3, 4*6]
    return (s == 0) ? 0 : (s < 6) ? 1 : (s < 9) ? 2 : (s == 9) ? 3 : 4;
}

// Wave = ONE position x 64 elements. seg is wave-uniform -> ALL weights are
// scalar loads (SGPR operands, free in v_fma): zero weight traffic in the
// vector pipes. This attacks the r0 diagnosis directly (1470 VALU/thread,
// 3x the essential math, mostly weight unpack/address overhead).
__global__ __launch_bounds__(1024) void attn_seg_kernel(
    const float* __restrict__ x,
    const float* __restrict__ Wq, const float* __restrict__ bq,
    const float* __restrict__ Wk, const float* __restrict__ bk,
    const float* __restrict__ Wv, const float* __restrict__ bv,
    const float* __restrict__ Wo, const float* __restrict__ bo,
    float* __restrict__ out, int nelems)
{
    __shared__ __align__(16) float lds[LDS_FLOATS];
    const int t = threadIdx.x;
    const int e = t & 63;                                   // lane: element
    const int s = __builtin_amdgcn_readfirstlane(t >> 6);   // wave: position (uniform)
    const int seg = seg_of(s);                              // uniform -> SALU
    const int ebase = (int)blockIdx.x << 6;
    const int eg = ebase + e;
    const bool valid = eg < nelems;

    // ---- x row for (elem eg, pos s): 24B per lane, 384B lane stride.
    // Block window = 24KB contiguous: first touch pulls the line, the other
    // ~2.7 waves touching it hit L1. Hidden by 8 waves/SIMD residency.
    float x0=0.f,x1=0.f,x2=0.f,x3=0.f,x4=0.f,x5=0.f;
    if (valid) {
        const float* xp = x + (size_t)eg * 96 + s * 6;
        float2 a = *(const float2*)(xp);
        float2 b = *(const float2*)(xp + 2);
        float2 c = *(const float2*)(xp + 4);
        x0=a.x; x1=a.y; x2=b.x; x3=b.y; x4=c.x; x5=c.y;
    }

    // ---- K,V projections: weights wave-uniform -> s_load, SGPR operands ----
    const float* wk = Wk + seg * 36;
    const float* wv = Wv + seg * 36;
    const float* bkp = bk + seg * 6;
    const float* bvp = bv + seg * 6;
    float kk[6], vv[6];
    #pragma unroll
    for (int j = 0; j < 6; ++j) {
        kk[j] = bkp[j] + x0*wk[j*6+0] + x1*wk[j*6+1] + x2*wk[j*6+2]
                       + x3*wk[j*6+3] + x4*wk[j*6+4] + x5*wk[j*6+5];
        vv[j] = bvp[j] + x0*wv[j*6+0] + x1*wv[j*6+1] + x2*wv[j*6+2]
                       + x3*wv[j*6+3] + x4*wv[j*6+4] + x5*wv[j*6+5];
    }

    // ---- publish interleaved K|V row (6x b64, 8B-aligned) ----
    {
        float* kv = &lds[e * KV_STRIDE + s * 12];
        *(float2*)(kv + 0)  = make_float2(kk[0], kk[1]);
        *(float2*)(kv + 2)  = make_float2(kk[2], kk[3]);
        *(float2*)(kv + 4)  = make_float2(kk[4], kk[5]);
        *(float2*)(kv + 6)  = make_float2(vv[0], vv[1]);
        *(float2*)(kv + 8)  = make_float2(vv[2], vv[3]);
        *(float2*)(kv + 10) = make_float2(vv[4], vv[5]);
    }

    // ---- Q projection (overlaps the LDS write drain) ----
    const float* wq = Wq + seg * 36;
    const float* bqp = bq + seg * 6;
    float q[6];
    #pragma unroll
    for (int j = 0; j < 6; ++j) {
        q[j] = (bqp[j] + x0*wq[j*6+0] + x1*wq[j*6+1] + x2*wq[j*6+2]
                       + x3*wq[j*6+3] + x4*wq[j*6+4] + x5*wq[j*6+5]) * QSCALE;
    }

    __syncthreads();   // K,V of all 16 positions visible

    // ---- fused scores -> exp2 -> sum -> PV over own element's 16 keys ----
    // One base VGPR + immediate offsets (k*48 + c*8 bytes, max 760 < 64K).
    const float* kvb = &lds[e * KV_STRIDE];
    float s0 = 0.f, s1 = 0.f;
    float c0=0.f,c1=0.f,c2=0.f,c3=0.f,c4=0.f,c5=0.f;
    #pragma unroll
    for (int k = 0; k < 16; ++k) {
        float2 ka = *(const float2*)(kvb + k*12 + 0);
        float2 kb = *(const float2*)(kvb + k*12 + 2);
        float2 kc = *(const float2*)(kvb + k*12 + 4);
        float e0 = __builtin_amdgcn_exp2f(q[0]*ka.x + q[1]*ka.y + q[2]*kb.x);
        float e1 = __builtin_amdgcn_exp2f(q[3]*kb.y + q[4]*kc.x + q[5]*kc.y);
        float2 va = *(const float2*)(kvb + k*12 + 6);
        float2 vb = *(const float2*)(kvb + k*12 + 8);
        float2 vc = *(const float2*)(kvb + k*12 + 10);
        s0 += e0; s1 += e1;
        c0 += e0*va.x; c1 += e0*va.y; c2 += e0*vb.x;
        c3 += e1*vb.y; c4 += e1*vc.x; c5 += e1*vc.y;
    }
    const float i0 = __builtin_amdgcn_rcpf(s0);
    const float i1 = __builtin_amdgcn_rcpf(s1);
    c0 *= i0; c1 *= i0; c2 *= i0;
    c3 *= i1; c4 *= i1; c5 *= i1;

    // ---- output projection: Wo,bo wave-uniform -> SGPR operands ----
    {
        float* ol = &lds[OUT_OFF + e * OUT_STRIDE + s * 6];
        #pragma unroll
        for (int i = 0; i < 6; ++i) {
            ol[i] = bo[i] + c0*Wo[i*6+0] + c1*Wo[i*6+1] + c2*Wo[i*6+2]
                          + c3*Wo[i*6+3] + c4*Wo[i*6+4] + c5*Wo[i*6+5];
        }
    }

    __syncthreads();   // all outputs staged

    // ---- coalesced store: thread t = (elem t>>4, pos t&15) -> 24B contiguous
    {
        const float* orow = &lds[OUT_OFF + (t >> 4) * OUT_STRIDE + (t & 15) * 6];
        if (ebase + (t >> 4) < nelems) {
            float* op = out + (size_t)ebase * 96 + t * 6;
            float2 a = make_float2(orow[0], orow[1]);
            float2 b = make_float2(orow[2], orow[3]);
            float2 c = make_float2(orow[4], orow[5]);
            *(float2*)(op)     = a;
            *(float2*)(op + 2) = b;
            *(float2*)(op + 4) = c;
        }
    }
}

extern "C" void kernel_launch(void* const* d_in, const int* in_sizes, int n_in,
                              void* d_out, int out_size, void* d_ws, size_t ws_size,
                              hipStream_t stream) {
    const float* x  = (const float*)d_in[0];
    const float* Wq = (const float*)d_in[1];
    const float* bq = (const float*)d_in[2];
    const float* Wk = (const float*)d_in[3];
    const float* bk = (const float*)d_in[4];
    const float* Wv = (const float*)d_in[5];
    const float* bv = (const float*)d_in[6];
    const float* Wo = (const float*)d_in[7];
    const float* bo = (const float*)d_in[8];
    float* out = (float*)d_out;

    const int nelems = in_sizes[0] / 96;        // batch elements
    const int grid   = (nelems + 63) / 64;      // 64 elements / block (1024 thr)
    attn_seg_kernel<<<grid, 1024, 0, stream>>>(x, Wq, bq, Wk, bk, Wv, bv, Wo, bo, out, nelems);
}